// Round 10
// baseline (136.083 us; speedup 1.0000x reference)
//
#include <hip/hip_runtime.h>
#include <hip/hip_bf16.h>

typedef __attribute__((ext_vector_type(8))) short short8v;
typedef __attribute__((ext_vector_type(4))) float f32x4;

#define DEVFN __device__ __forceinline__

DEVFN unsigned short f2bf(float x) {
  __hip_bfloat16 h = __float2bfloat16(x);
  return *reinterpret_cast<unsigned short*>(&h);
}

DEVFN float bf2f(unsigned short u) {
  unsigned int x = ((unsigned int)u) << 16;
  float f;
  __builtin_memcpy(&f, &x, 4);
  return f;
}

DEVFN void gload16(const void* g, void* l) {
  __builtin_amdgcn_global_load_lds(
      (const __attribute__((address_space(1))) void*)g,
      (__attribute__((address_space(3))) void*)l, 16, 0, 0);
}

// s_waitcnt vmcnt(N) only (expcnt/lgkmcnt = no-wait). gfx9 encoding:
// vmcnt[3:0]=bits[3:0], vmcnt[5:4]=bits[15:14], expcnt=bits[6:4], lgkm=bits[11:8]
template <int N>
DEVFN void wait_vmcnt() {
  __builtin_amdgcn_s_waitcnt((N & 15) | ((N >> 4) << 14) | (7 << 4) | (15 << 8));
}

// Weight transpose-casts + q_start only.
__global__ __launch_bounds__(256) void prep(
    const float* __restrict__ Wk, const float* __restrict__ Wv,
    const float* __restrict__ Wq, const float* __restrict__ Wo,
    const float* __restrict__ Wg,
    unsigned short* __restrict__ Btkv, unsigned short* __restrict__ Btq,
    unsigned short* __restrict__ Bto, unsigned short* __restrict__ Btg,
    const int* __restrict__ q_idx, int* __restrict__ q_start, int Q, int E) {
  const int b = blockIdx.x, t = threadIdx.x;
  if (b < 256) {
    const int wi = b >> 6, bb = b & 63;
    const float* W = (wi == 0) ? Wk : (wi == 1) ? Wv : (wi == 2) ? Wq : Wo;
    unsigned short* O = (wi == 0) ? Btkv : (wi == 1) ? (Btkv + 65536)
                     : (wi == 2) ? Btq : Bto;
    for (int id = bb * 256 + t; id < 65536; id += 64 * 256) {
      const int n = id >> 8, k = id & 255;
      O[id] = f2bf(W[k * 256 + n]);
    }
  } else if (b < 272) {
    for (int id = (b - 256) * 256 + t; id < 16384; id += 16 * 256) {
      const int n = id >> 6, k = id & 63;
      Btg[id] = f2bf(Wg[k * 256 + n]);
    }
  } else {
    const int q = (b - 272) * 256 + t;
    if (q <= Q) {
      int lo = 0, hi = E;
      while (lo < hi) { int mid = (lo + hi) >> 1; if (q_idx[mid] < q) lo = mid + 1; else hi = mid; }
      q_start[q] = lo;
    }
  }
}

// Barrier-free direct GEMM: C[M][NB] = A[M][K] @ Bt[NB][K]^T.
// Block = 512 thr (8 waves), BM=128 (16 rows/wave), BN=64.
// A: loaded DIRECTLY into MFMA fragment registers (lane l: row l&15,
// k-chunk (l>>4)*8; all KT K-tiles issued upfront -> full MLP), fp32 cvt'd
// in-reg once. B: 64xK bf16 staged in LDS ONCE (chunk-XOR swizzle
// cs = c ^ (col&7); gload16 linear dest + inverse-swizzled source, rule 21).
// One s_barrier per kernel; compiler handles all lgkm/vm waits in the loop.
// OUT_MODE: 0 = fp32, 1 = bf16, at row*ldc+col.
template <int KT, bool A_F32, int OUT_MODE, bool HAS_BIAS>
__global__ __launch_bounds__(512, 3) void gemm_direct(
    const void* __restrict__ Av, const unsigned short* __restrict__ Bt,
    void* __restrict__ Cv, const float* __restrict__ bias, int ldc) {
  constexpr int K = KT * 32;
  constexpr int BGL = (64 * K * 2) / (512 * 16);   // B gloads per thread
  constexpr int ATOT = KT * (A_F32 ? 2 : 1);       // A loads per thread
  __shared__ unsigned short Bs[64 * K];

  const int t = threadIdx.x;
  const int w = t >> 6, l = t & 63;
  const int lr = l & 15, lk = l >> 4;

  // XCD-bijective swizzle (all launches have nwg % 8 == 0)
  const int gx = gridDim.x;
  const int nwg = gx * gridDim.y;
  const int id = blockIdx.y * gx + blockIdx.x;
  const int swz = (id & 7) * (nwg >> 3) + (id >> 3);
  const int n0 = (swz % gx) * 64;
  const int m0 = (swz / gx) * 128;

  // ---- B stage (once): linear LDS dest, inverse-swizzled global src ----
#pragma unroll
  for (int s = 0; s < BGL; ++s) {
    const int o = s * 8192 + t * 16;          // byte offset in Bs
    const int col = o / (K * 2);
    const int cslot = (o % (K * 2)) / 16;
    const int c = cslot ^ (col & 7);
    gload16(Bt + (size_t)(n0 + col) * K + c * 8,
            (char*)Bs + s * 8192 + (t & ~63) * 16);
  }
  __builtin_amdgcn_sched_barrier(0);

  // ---- A loads: all K-tiles upfront, straight into fragment layout ----
  f32x4 avf[KT > 0 ? KT : 1][2];
  short8v avb[KT > 0 ? KT : 1];
  if (A_F32) {
    const float* Af = (const float*)Av + (size_t)(m0 + w * 16 + lr) * K + lk * 8;
#pragma unroll
    for (int kt = 0; kt < KT; ++kt) {
      avf[kt][0] = *(const f32x4*)(Af + kt * 32);
      avf[kt][1] = *(const f32x4*)(Af + kt * 32 + 4);
    }
  } else {
    const unsigned short* Ab =
        (const unsigned short*)Av + (size_t)(m0 + w * 16 + lr) * K + lk * 8;
#pragma unroll
    for (int kt = 0; kt < KT; ++kt)
      avb[kt] = *(const short8v*)(Ab + kt * 32);
  }
  __builtin_amdgcn_sched_barrier(0);

  wait_vmcnt<ATOT>();                 // all B gloads landed (A may be in flight)
  __builtin_amdgcn_s_barrier();       // the only barrier
  __builtin_amdgcn_sched_barrier(0);

  f32x4 acc[4];
#pragma unroll
  for (int n = 0; n < 4; ++n) acc[n] = (f32x4){0.f, 0.f, 0.f, 0.f};

#pragma unroll
  for (int kt = 0; kt < KT; ++kt) {
    short8v a;
    if (A_F32) {
      const f32x4 lo = avf[kt][0], hi = avf[kt][1];
      short8v r;
      r[0] = (short)f2bf(lo[0]); r[1] = (short)f2bf(lo[1]);
      r[2] = (short)f2bf(lo[2]); r[3] = (short)f2bf(lo[3]);
      r[4] = (short)f2bf(hi[0]); r[5] = (short)f2bf(hi[1]);
      r[6] = (short)f2bf(hi[2]); r[7] = (short)f2bf(hi[3]);
      a = r;
    } else {
      a = avb[kt];
    }
    short8v b[4];
#pragma unroll
    for (int n = 0; n < 4; ++n) {
      const int col = n * 16 + lr;
      const int cs = (kt * 4 + lk) ^ (col & 7);
      b[n] = *(const short8v*)((const char*)Bs + col * (K * 2) + cs * 16);
    }
#pragma unroll
    for (int n = 0; n < 4; ++n)
      acc[n] = __builtin_amdgcn_mfma_f32_16x16x32_bf16(a, b[n], acc[n], 0, 0, 0);
  }

  // epilogue: C/D layout col = lane&15, row = (lane>>4)*4 + reg
#pragma unroll
  for (int n = 0; n < 4; ++n) {
    const int col = n0 + n * 16 + lr;
    const int rbase = m0 + w * 16 + lk * 4;
    float bv = 0.f;
    if (HAS_BIAS) bv = bias[col];
#pragma unroll
    for (int r = 0; r < 4; ++r) {
      const float val = acc[n][r] + bv;
      if (OUT_MODE == 0) {
        ((float*)Cv)[(size_t)(rbase + r) * ldc + col] = val;
      } else {
        ((unsigned short*)Cv)[(size_t)(rbase + r) * ldc + col] = f2bf(val);
      }
    }
  }
}

// One block (256 thr) per query; 8 edge streams; 32 lanes per edge,
// 8 dims per lane. KV planar [N][512] = K|V. No online max (exact).
__global__ __launch_bounds__(256) void edge_attn(
    const int* __restrict__ s_idx, const int* __restrict__ q_start,
    const uint4* __restrict__ KV4, const unsigned short* __restrict__ Qf,
    const unsigned short* __restrict__ Gf, unsigned short* __restrict__ out_pre,
    const float* __restrict__ log_tau) {
  const int q = blockIdx.x;
  const int t = threadIdx.x;
  const int w = t >> 6;
  const int lane = t & 63;
  const int stream = w * 2 + (lane >> 5);
  const int sl = lane & 31;
  const int start = q_start[q], end = q_start[q + 1];

  const float tau = __expf(log_tau[0]);
  const float rs = 1.0f / (5.656854249492381f * tau);

  float qv[8];
  {
    uint4 qw = *(const uint4*)(Qf + (size_t)q * 256 + sl * 8);
    const unsigned int ws_[4] = {qw.x, qw.y, qw.z, qw.w};
#pragma unroll
    for (int j = 0; j < 4; ++j) {
      qv[2 * j]     = bf2f((unsigned short)(ws_[j] & 0xffffu)) * rs;
      qv[2 * j + 1] = bf2f((unsigned short)(ws_[j] >> 16)) * rs;
    }
  }

  float o[8];
#pragma unroll
  for (int j = 0; j < 8; ++j) o[j] = 0.f;
  float lsum_p = 0.f;

  __shared__ int sseg[1024];

  for (int cb = start; cb < end; cb += 1024) {
    const int nb = min(1024, end - cb);
    __syncthreads();
    for (int jj = t; jj < nb; jj += 256) sseg[jj] = s_idx[cb + jj];
    __syncthreads();

    int j = stream;
    uint4 kc, vc;
    if (j < nb) {
      const uint4* bp = KV4 + (size_t)sseg[j] * 64;
      kc = bp[sl];
      vc = bp[32 + sl];
    }
    while (j < nb) {
      const int jn = j + 8;
      const bool more = jn < nb;
      uint4 kcn, vcn;
      if (more) {
        const uint4* bpn = KV4 + (size_t)sseg[jn] * 64;
        kcn = bpn[sl];
        vcn = bpn[32 + sl];
      }
      const unsigned int kw[4] = {kc.x, kc.y, kc.z, kc.w};
      float p = 0.f;
#pragma unroll
      for (int jj = 0; jj < 4; ++jj) {
        p = fmaf(qv[2 * jj], bf2f((unsigned short)(kw[jj] & 0xffffu)), p);
        p = fmaf(qv[2 * jj + 1], bf2f((unsigned short)(kw[jj] >> 16)), p);
      }
      p += __shfl_xor(p, 1);
      p += __shfl_xor(p, 2);
      const float ew = __expf(p);
      lsum_p += ew;
      const unsigned int vw[4] = {vc.x, vc.y, vc.z, vc.w};
#pragma unroll
      for (int jj = 0; jj < 4; ++jj) {
        o[2 * jj]     = fmaf(ew, bf2f((unsigned short)(vw[jj] & 0xffffu)), o[2 * jj]);
        o[2 * jj + 1] = fmaf(ew, bf2f((unsigned short)(vw[jj] >> 16)), o[2 * jj + 1]);
      }
      j = jn;
      kc = kcn;
      vc = vcn;
    }
  }

  __shared__ float o_sh[8][256];
  __shared__ float l_sh[8][8];
  *(float4*)&o_sh[stream][sl * 8]     = (float4){o[0], o[1], o[2], o[3]};
  *(float4*)&o_sh[stream][sl * 8 + 4] = (float4){o[4], o[5], o[6], o[7]};
  if ((sl & 3) == 0) l_sh[stream][sl >> 2] = lsum_p;
  __syncthreads();

  float osum = 0.f, lsum = 0.f;
  const int h = t >> 5;
#pragma unroll
  for (int s = 0; s < 8; ++s) {
    osum += o_sh[s][t];
    lsum += l_sh[s][h];
  }
  const float inv = 1.0f / fmaxf(lsum, 1e-8f);
  float res = 0.f;
  if (end > start) res = osum * inv + (lsum * inv) * bf2f(Gf[(size_t)q * 256 + t]);
  out_pre[(size_t)q * 256 + t] = f2bf(res);
}

extern "C" void kernel_launch(void* const* d_in, const int* in_sizes, int n_in,
                              void* d_out, int out_size, void* d_ws, size_t ws_size,
                              hipStream_t stream) {
  const float* query   = (const float*)d_in[0];
  const float* support = (const float*)d_in[1];
  const float* geo     = (const float*)d_in[2];
  const int*   q_idx   = (const int*)d_in[3];
  const int*   s_idx   = (const int*)d_in[4];
  const float* Wq      = (const float*)d_in[6];
  const float* Wk      = (const float*)d_in[7];
  const float* Wv      = (const float*)d_in[8];
  const float* Wg      = (const float*)d_in[9];
  const float* Wo      = (const float*)d_in[10];
  const float* bo      = (const float*)d_in[11];
  const float* log_tau = (const float*)d_in[12];

  const int D = 256;
  const int Q = in_sizes[0] / D;   // 8192
  const int N = in_sizes[1] / D;   // 65536
  const int E = in_sizes[3];       // 262144

  unsigned short* ws = (unsigned short*)d_ws;
  unsigned short* KV   = ws;                       // [N][512] bf16 planar K|V
  unsigned short* Qf   = KV   + (size_t)N * 512;   // bf16 [Q][256]
  unsigned short* Gf   = Qf   + (size_t)Q * 256;   // bf16 [Q][256]
  unsigned short* Opre = Gf   + (size_t)Q * 256;   // bf16 [Q][256]
  unsigned short* Btkv = Opre + (size_t)Q * 256;   // [512][256] = [Wk^T; Wv^T]
  unsigned short* Btq  = Btkv + 512 * 256;         // [256][256]
  unsigned short* Btg  = Btq  + 256 * 256;         // [256][64]
  unsigned short* Bto  = Btg  + 256 * 64;          // [256][256]
  int* q_start = (int*)(Bto + 256 * 256);          // [Q+1]

  prep<<<dim3(305), dim3(256), 0, stream>>>(Wk, Wv, Wq, Wo, Wg,
                                            Btkv, Btq, Bto, Btg, q_idx, q_start, Q, E);

  // KV projection: A direct-to-reg, B once in LDS, planar K|V out
  gemm_direct<8, true, 1, false><<<dim3(8, N / 128), dim3(512), 0, stream>>>(
      support, Btkv, (void*)KV, nullptr, 512);
  gemm_direct<8, true, 1, false><<<dim3(4, Q / 128), dim3(512), 0, stream>>>(
      query, Btq, (void*)Qf, nullptr, 256);
  gemm_direct<2, true, 1, false><<<dim3(4, Q / 128), dim3(512), 0, stream>>>(
      geo, Btg, (void*)Gf, nullptr, 256);

  edge_attn<<<dim3(Q), dim3(256), 0, stream>>>(s_idx, q_start, (const uint4*)KV,
                                               Qf, Gf, Opre, log_tau);

  gemm_direct<8, false, 0, true><<<dim3(4, Q / 128), dim3(512), 0, stream>>>(
      Opre, Bto, d_out, bo, 256);
}

// Round 11
// 110.751 us; speedup vs baseline: 1.2287x; 1.2287x over previous
//
#include <hip/hip_runtime.h>
#include <hip/hip_bf16.h>

typedef __attribute__((ext_vector_type(8))) short short8v;
typedef __attribute__((ext_vector_type(4))) float f32x4;

#define DEVFN __device__ __forceinline__

DEVFN unsigned short f2bf(float x) {
  __hip_bfloat16 h = __float2bfloat16(x);
  return *reinterpret_cast<unsigned short*>(&h);
}

DEVFN float bf2f(unsigned short u) {
  unsigned int x = ((unsigned int)u) << 16;
  float f;
  __builtin_memcpy(&f, &x, 4);
  return f;
}

DEVFN void gload16(const void* g, void* l) {
  __builtin_amdgcn_global_load_lds(
      (const __attribute__((address_space(1))) void*)g,
      (__attribute__((address_space(3))) void*)l, 16, 0, 0);
}

// All preprocessing: bf16 casts of support/query/geo, weight transpose-casts,
// q_start binary search. (Round-3 version — the separate cast pass ties the
// fused variants overall and enables the fast 4-load GEMM loop.)
__global__ __launch_bounds__(256) void prep(
    const float* __restrict__ support, const float* __restrict__ query,
    const float* __restrict__ geo,
    const float* __restrict__ Wk, const float* __restrict__ Wv,
    const float* __restrict__ Wq, const float* __restrict__ Wo,
    const float* __restrict__ Wg,
    unsigned short* __restrict__ Abf, unsigned short* __restrict__ Qbf,
    unsigned short* __restrict__ Gbf,
    unsigned short* __restrict__ Btkv, unsigned short* __restrict__ Btq,
    unsigned short* __restrict__ Bto, unsigned short* __restrict__ Btg,
    const int* __restrict__ q_idx, int* __restrict__ q_start,
    int N, int Q, int E) {
  const int b = blockIdx.x, t = threadIdx.x;
  if (b < 2048) {                       // support cast: N*64 float4s
    const int n4 = N * 64;
    for (int i = b * 256 + t; i < n4; i += 2048 * 256) {
      float4 v = ((const float4*)support)[i];
      ushort4 o = {f2bf(v.x), f2bf(v.y), f2bf(v.z), f2bf(v.w)};
      ((ushort4*)Abf)[i] = o;
    }
  } else if (b < 2560) {                // query cast: Q*64 float4s
    const int n4 = Q * 64;
    for (int i = (b - 2048) * 256 + t; i < n4; i += 512 * 256) {
      float4 v = ((const float4*)query)[i];
      ushort4 o = {f2bf(v.x), f2bf(v.y), f2bf(v.z), f2bf(v.w)};
      ((ushort4*)Qbf)[i] = o;
    }
  } else if (b < 2688) {                // geo cast: Q*16 float4s
    const int n4 = Q * 16;
    for (int i = (b - 2560) * 256 + t; i < n4; i += 128 * 256) {
      float4 v = ((const float4*)geo)[i];
      ushort4 o = {f2bf(v.x), f2bf(v.y), f2bf(v.z), f2bf(v.w)};
      ((ushort4*)Gbf)[i] = o;
    }
  } else if (b < 2944) {                // Wk/Wv/Wq/Wo transpose-cast
    const int wi = (b - 2688) >> 6, bb = (b - 2688) & 63;
    const float* W = (wi == 0) ? Wk : (wi == 1) ? Wv : (wi == 2) ? Wq : Wo;
    unsigned short* O = (wi == 0) ? Btkv : (wi == 1) ? (Btkv + 65536)
                     : (wi == 2) ? Btq : Bto;
    for (int id = bb * 256 + t; id < 65536; id += 64 * 256) {
      const int n = id >> 8, k = id & 255;
      O[id] = f2bf(W[k * 256 + n]);
    }
  } else if (b < 2960) {                // Wg [64][256] -> Btg [256][64]
    for (int id = (b - 2944) * 256 + t; id < 16384; id += 16 * 256) {
      const int n = id >> 6, k = id & 63;
      Btg[id] = f2bf(Wg[k * 256 + n]);
    }
  } else {                              // q_start
    const int q = (b - 2960) * 256 + t;
    if (q <= Q) {
      int lo = 0, hi = E;
      while (lo < hi) { int mid = (lo + hi) >> 1; if (q_idx[mid] < q) lo = mid + 1; else hi = mid; }
      q_start[q] = lo;
    }
  }
}

// Deep-pipelined GEMM: C = A(bf16 [M][K]) @ Bt(bf16 [NB][K])^T.
// 128x128 tile, BK=32, 4 waves (2x2), 4x4 frags of mfma_f32_16x16x32_bf16.
// 3 LDS buffers, depth-2 prefetch: loads stay in flight ACROSS barriers;
// steady-state wait is vmcnt(8), never 0 until the tail (T3/T4).
// Per iter: B1 (overwrite guard) -> stage(tt+2) -> vmcnt(counted) ->
// B2 (tile tt visible) -> compute(tt). All indices compile-time (full unroll).
// Chunk-XOR swizzle cs = c ^ ((row>>1)&3) on both sides (0 conflicts, r3).
// OUT_MODE: 0 = fp32, 1 = bf16, at row*ldc+col.
template <int KT, int OUT_MODE, bool HAS_BIAS>
__global__ __launch_bounds__(256) void gemm_pipe(
    const unsigned short* __restrict__ A, const unsigned short* __restrict__ Bt,
    void* __restrict__ Cv, const float* __restrict__ bias, int ldc) {
  constexpr int K = KT * 32;
  __shared__ unsigned short As[3][128 * 32];  // 8 KB each
  __shared__ unsigned short Bs[3][128 * 32];  // 8 KB each

  const int t = threadIdx.x;
  const int wv = t >> 6, l = t & 63;
  const int wr = wv >> 1, wc = wv & 1;
  const int lr = l & 15, lk = l >> 4;

  // XCD-bijective swizzle (all launches have nwg % 8 == 0)
  const int gx = gridDim.x;
  const int nwg = gx * gridDim.y;
  const int orig = blockIdx.y * gx + blockIdx.x;
  const int swz = (orig & 7) * (nwg >> 3) + (orig >> 3);
  const int n0 = (swz % gx) * 128;
  const int m0 = (swz / gx) * 128;

  f32x4 acc[4][4];
#pragma unroll
  for (int m = 0; m < 4; ++m)
#pragma unroll
    for (int n = 0; n < 4; ++n) acc[m][n] = (f32x4){0.f, 0.f, 0.f, 0.f};

  const int wbase = (t & ~63) * 16;  // wave-uniform LDS byte base for gload16

  auto stage = [&](int buf, int k0) {
#pragma unroll
    for (int s = 0; s < 2; ++s) {
      const int cidx = s * 256 + t;
      const int row = cidx >> 2, c = cidx & 3;
      const int cs = c ^ ((row >> 1) & 3);
      gload16(A + (size_t)(m0 + row) * K + k0 + cs * 8,
              (char*)&As[buf][0] + (size_t)s * 4096 + wbase);
    }
#pragma unroll
    for (int s = 0; s < 2; ++s) {
      const int cidx = s * 256 + t;
      const int row = cidx >> 2, c = cidx & 3;
      const int cs = c ^ ((row >> 1) & 3);
      gload16(Bt + (size_t)(n0 + row) * K + k0 + cs * 8,
              (char*)&Bs[buf][0] + (size_t)s * 4096 + wbase);
    }
  };

  auto compute = [&](int buf) {
    short8v a[4], b[4];
#pragma unroll
    for (int m = 0; m < 4; ++m) {
      const int row = wr * 64 + m * 16 + lr;
      const int cs = lk ^ ((row >> 1) & 3);
      a[m] = *(const short8v*)&As[buf][row * 32 + cs * 8];
    }
#pragma unroll
    for (int n = 0; n < 4; ++n) {
      const int row = wc * 64 + n * 16 + lr;
      const int cs = lk ^ ((row >> 1) & 3);
      b[n] = *(const short8v*)&Bs[buf][row * 32 + cs * 8];
    }
#pragma unroll
    for (int m = 0; m < 4; ++m)
#pragma unroll
      for (int n = 0; n < 4; ++n)
        acc[m][n] = __builtin_amdgcn_mfma_f32_16x16x32_bf16(a[m], b[n], acc[m][n], 0, 0, 0);
  };

  // prologue: 2 tiles in flight (8 loads/thread)
  stage(0, 0);
  if (KT > 1) stage(1, 32);

#pragma unroll
  for (int tt = 0; tt < KT; ++tt) {
    __builtin_amdgcn_s_barrier();        // B1: compute(tt-1) reads complete
    __builtin_amdgcn_sched_barrier(0);
    if (tt + 2 < KT) stage((tt + 2) % 3, (tt + 2) * 32);
    const int rem = (tt + 2 < KT ? tt + 2 : KT - 1) - tt;  // folds per-iter
    if (rem >= 2)      asm volatile("s_waitcnt vmcnt(8)" ::: "memory");
    else if (rem == 1) asm volatile("s_waitcnt vmcnt(4)" ::: "memory");
    else               asm volatile("s_waitcnt vmcnt(0)" ::: "memory");
    __builtin_amdgcn_s_barrier();        // B2: tile tt visible to all
    __builtin_amdgcn_sched_barrier(0);
    compute(tt % 3);
  }

  // epilogue: C/D layout col = lane&15, row = (lane>>4)*4 + reg (m89-verified)
#pragma unroll
  for (int m = 0; m < 4; ++m)
#pragma unroll
    for (int n = 0; n < 4; ++n) {
      const f32x4 v = acc[m][n];
      const int col = n0 + wc * 64 + n * 16 + lr;
      const int rbase = m0 + wr * 64 + m * 16 + lk * 4;
      float bv = 0.f;
      if (HAS_BIAS) bv = bias[col];
#pragma unroll
      for (int r = 0; r < 4; ++r) {
        const float val = v[r] + bv;
        if (OUT_MODE == 0) {
          ((float*)Cv)[(size_t)(rbase + r) * ldc + col] = val;
        } else {
          ((unsigned short*)Cv)[(size_t)(rbase + r) * ldc + col] = f2bf(val);
        }
      }
    }
}

// One block (256 thr) per query; 8 edge streams; 32 lanes per edge,
// 8 dims per lane. KV planar [N][512] = K|V. No online max (exact).
__global__ __launch_bounds__(256) void edge_attn(
    const int* __restrict__ s_idx, const int* __restrict__ q_start,
    const uint4* __restrict__ KV4, const unsigned short* __restrict__ Qf,
    const unsigned short* __restrict__ Gf, unsigned short* __restrict__ out_pre,
    const float* __restrict__ log_tau) {
  const int q = blockIdx.x;
  const int t = threadIdx.x;
  const int w = t >> 6;
  const int lane = t & 63;
  const int stream = w * 2 + (lane >> 5);
  const int sl = lane & 31;
  const int start = q_start[q], end = q_start[q + 1];

  const float tau = __expf(log_tau[0]);
  const float rs = 1.0f / (5.656854249492381f * tau);

  float qv[8];
  {
    uint4 qw = *(const uint4*)(Qf + (size_t)q * 256 + sl * 8);
    const unsigned int ws_[4] = {qw.x, qw.y, qw.z, qw.w};
#pragma unroll
    for (int j = 0; j < 4; ++j) {
      qv[2 * j]     = bf2f((unsigned short)(ws_[j] & 0xffffu)) * rs;
      qv[2 * j + 1] = bf2f((unsigned short)(ws_[j] >> 16)) * rs;
    }
  }

  float o[8];
#pragma unroll
  for (int j = 0; j < 8; ++j) o[j] = 0.f;
  float lsum_p = 0.f;

  __shared__ int sseg[1024];

  for (int cb = start; cb < end; cb += 1024) {
    const int nb = min(1024, end - cb);
    __syncthreads();
    for (int jj = t; jj < nb; jj += 256) sseg[jj] = s_idx[cb + jj];
    __syncthreads();

    int j = stream;
    uint4 kc, vc;
    if (j < nb) {
      const uint4* bp = KV4 + (size_t)sseg[j] * 64;
      kc = bp[sl];
      vc = bp[32 + sl];
    }
    while (j < nb) {
      const int jn = j + 8;
      const bool more = jn < nb;
      uint4 kcn, vcn;
      if (more) {
        const uint4* bpn = KV4 + (size_t)sseg[jn] * 64;
        kcn = bpn[sl];
        vcn = bpn[32 + sl];
      }
      const unsigned int kw[4] = {kc.x, kc.y, kc.z, kc.w};
      float p = 0.f;
#pragma unroll
      for (int jj = 0; jj < 4; ++jj) {
        p = fmaf(qv[2 * jj], bf2f((unsigned short)(kw[jj] & 0xffffu)), p);
        p = fmaf(qv[2 * jj + 1], bf2f((unsigned short)(kw[jj] >> 16)), p);
      }
      p += __shfl_xor(p, 1);
      p += __shfl_xor(p, 2);
      const float ew = __expf(p);
      lsum_p += ew;
      const unsigned int vw[4] = {vc.x, vc.y, vc.z, vc.w};
#pragma unroll
      for (int jj = 0; jj < 4; ++jj) {
        o[2 * jj]     = fmaf(ew, bf2f((unsigned short)(vw[jj] & 0xffffu)), o[2 * jj]);
        o[2 * jj + 1] = fmaf(ew, bf2f((unsigned short)(vw[jj] >> 16)), o[2 * jj + 1]);
      }
      j = jn;
      kc = kcn;
      vc = vcn;
    }
  }

  __shared__ float o_sh[8][256];
  __shared__ float l_sh[8][8];
  *(float4*)&o_sh[stream][sl * 8]     = (float4){o[0], o[1], o[2], o[3]};
  *(float4*)&o_sh[stream][sl * 8 + 4] = (float4){o[4], o[5], o[6], o[7]};
  if ((sl & 3) == 0) l_sh[stream][sl >> 2] = lsum_p;
  __syncthreads();

  float osum = 0.f, lsum = 0.f;
  const int h = t >> 5;
#pragma unroll
  for (int s = 0; s < 8; ++s) {
    osum += o_sh[s][t];
    lsum += l_sh[s][h];
  }
  const float inv = 1.0f / fmaxf(lsum, 1e-8f);
  float res = 0.f;
  if (end > start) res = osum * inv + (lsum * inv) * bf2f(Gf[(size_t)q * 256 + t]);
  out_pre[(size_t)q * 256 + t] = f2bf(res);
}

extern "C" void kernel_launch(void* const* d_in, const int* in_sizes, int n_in,
                              void* d_out, int out_size, void* d_ws, size_t ws_size,
                              hipStream_t stream) {
  const float* query   = (const float*)d_in[0];
  const float* support = (const float*)d_in[1];
  const float* geo     = (const float*)d_in[2];
  const int*   q_idx   = (const int*)d_in[3];
  const int*   s_idx   = (const int*)d_in[4];
  const float* Wq      = (const float*)d_in[6];
  const float* Wk      = (const float*)d_in[7];
  const float* Wv      = (const float*)d_in[8];
  const float* Wg      = (const float*)d_in[9];
  const float* Wo      = (const float*)d_in[10];
  const float* bo      = (const float*)d_in[11];
  const float* log_tau = (const float*)d_in[12];

  const int D = 256;
  const int Q = in_sizes[0] / D;   // 8192
  const int N = in_sizes[1] / D;   // 65536
  const int E = in_sizes[3];       // 262144

  unsigned short* ws = (unsigned short*)d_ws;
  unsigned short* KV   = ws;                       // [N][512] bf16 planar K|V
  unsigned short* Abf  = KV   + (size_t)N * 512;   // support bf16 [N][256]
  unsigned short* Qbf  = Abf  + (size_t)N * 256;   // query bf16 [Q][256]
  unsigned short* Gbf  = Qbf  + (size_t)Q * 256;   // geo bf16 [Q][64]
  unsigned short* Qf   = Gbf  + (size_t)Q * 64;    // bf16 [Q][256]
  unsigned short* Gf   = Qf   + (size_t)Q * 256;   // bf16 [Q][256]
  unsigned short* Opre = Gf   + (size_t)Q * 256;   // bf16 [Q][256]
  unsigned short* Btkv = Opre + (size_t)Q * 256;   // [512][256] = [Wk^T; Wv^T]
  unsigned short* Btq  = Btkv + 512 * 256;         // [256][256]
  unsigned short* Btg  = Btq  + 256 * 256;         // [256][64]
  unsigned short* Bto  = Btg  + 256 * 64;          // [256][256]
  int* q_start = (int*)(Bto + 256 * 256);          // [Q+1]

  dim3 blk(256);

  prep<<<dim3(2993), blk, 0, stream>>>(
      support, query, geo, Wk, Wv, Wq, Wo, Wg,
      Abf, Qbf, Gbf, Btkv, Btq, Bto, Btg, q_idx, q_start, N, Q, E);

  // KV projection: planar K|V out (ldc=512)
  gemm_pipe<8, 1, false><<<dim3(4, N / 128), blk, 0, stream>>>(
      Abf, Btkv, (void*)KV, nullptr, 512);
  gemm_pipe<8, 1, false><<<dim3(2, Q / 128), blk, 0, stream>>>(
      Qbf, Btq, (void*)Qf, nullptr, 256);
  gemm_pipe<2, 1, false><<<dim3(2, Q / 128), blk, 0, stream>>>(
      Gbf, Btg, (void*)Gf, nullptr, 256);

  edge_attn<<<dim3(Q), blk, 0, stream>>>(s_idx, q_start, (const uint4*)KV,
                                         Qf, Gf, Opre, log_tau);

  gemm_pipe<8, 0, true><<<dim3(2, Q / 128), blk, 0, stream>>>(
      Opre, Bto, d_out, bo, 256);
}

// Round 13
// 102.549 us; speedup vs baseline: 1.3270x; 1.0800x over previous
//
#include <hip/hip_runtime.h>
#include <hip/hip_bf16.h>

typedef __attribute__((ext_vector_type(8))) short short8v;
typedef __attribute__((ext_vector_type(4))) float f32x4;

#define DEVFN __device__ __forceinline__

DEVFN unsigned short f2bf(float x) {
  __hip_bfloat16 h = __float2bfloat16(x);
  return *reinterpret_cast<unsigned short*>(&h);
}

DEVFN float bf2f(unsigned short u) {
  unsigned int x = ((unsigned int)u) << 16;
  float f;
  __builtin_memcpy(&f, &x, 4);
  return f;
}

DEVFN void gload16(const void* g, void* l) {
  __builtin_amdgcn_global_load_lds(
      (const __attribute__((address_space(1))) void*)g,
      (__attribute__((address_space(3))) void*)l, 16, 0, 0);
}

// All preprocessing: bf16 casts of support/query/geo, weight transpose-casts,
// q_start binary search.
__global__ __launch_bounds__(256) void prep(
    const float* __restrict__ support, const float* __restrict__ query,
    const float* __restrict__ geo,
    const float* __restrict__ Wk, const float* __restrict__ Wv,
    const float* __restrict__ Wq, const float* __restrict__ Wo,
    const float* __restrict__ Wg,
    unsigned short* __restrict__ Abf, unsigned short* __restrict__ Qbf,
    unsigned short* __restrict__ Gbf,
    unsigned short* __restrict__ Btkv, unsigned short* __restrict__ Btq,
    unsigned short* __restrict__ Bto, unsigned short* __restrict__ Btg,
    const int* __restrict__ q_idx, int* __restrict__ q_start,
    int N, int Q, int E) {
  const int b = blockIdx.x, t = threadIdx.x;
  if (b < 2048) {                       // support cast: N*64 float4s
    const int n4 = N * 64;
    for (int i = b * 256 + t; i < n4; i += 2048 * 256) {
      float4 v = ((const float4*)support)[i];
      ushort4 o = {f2bf(v.x), f2bf(v.y), f2bf(v.z), f2bf(v.w)};
      ((ushort4*)Abf)[i] = o;
    }
  } else if (b < 2560) {                // query cast: Q*64 float4s
    const int n4 = Q * 64;
    for (int i = (b - 2048) * 256 + t; i < n4; i += 512 * 256) {
      float4 v = ((const float4*)query)[i];
      ushort4 o = {f2bf(v.x), f2bf(v.y), f2bf(v.z), f2bf(v.w)};
      ((ushort4*)Qbf)[i] = o;
    }
  } else if (b < 2688) {                // geo cast: Q*16 float4s
    const int n4 = Q * 16;
    for (int i = (b - 2560) * 256 + t; i < n4; i += 128 * 256) {
      float4 v = ((const float4*)geo)[i];
      ushort4 o = {f2bf(v.x), f2bf(v.y), f2bf(v.z), f2bf(v.w)};
      ((ushort4*)Gbf)[i] = o;
    }
  } else if (b < 2944) {                // Wk/Wv/Wq/Wo transpose-cast
    const int wi = (b - 2688) >> 6, bb = (b - 2688) & 63;
    const float* W = (wi == 0) ? Wk : (wi == 1) ? Wv : (wi == 2) ? Wq : Wo;
    unsigned short* O = (wi == 0) ? Btkv : (wi == 1) ? (Btkv + 65536)
                     : (wi == 2) ? Btq : Bto;
    for (int id = bb * 256 + t; id < 65536; id += 64 * 256) {
      const int n = id >> 8, k = id & 255;
      O[id] = f2bf(W[k * 256 + n]);
    }
  } else if (b < 2960) {                // Wg [64][256] -> Btg [256][64]
    for (int id = (b - 2944) * 256 + t; id < 16384; id += 16 * 256) {
      const int n = id >> 6, k = id & 63;
      Btg[id] = f2bf(Wg[k * 256 + n]);
    }
  } else {                              // q_start
    const int q = (b - 2960) * 256 + t;
    if (q <= Q) {
      int lo = 0, hi = E;
      while (lo < hi) { int mid = (lo + hi) >> 1; if (q_idx[mid] < q) lo = mid + 1; else hi = mid; }
      q_start[q] = lo;
    }
  }
}

// Deep-pipelined GEMM body: C = A(bf16 [M][K]) @ Bt(bf16 [NB][K])^T.
// 128x128 tile, BK=32, 4 waves (2x2), 4x4 frags of mfma_f32_16x16x32_bf16.
// 3 LDS buffers, depth-2 prefetch, counted vmcnt (never 0 until tail) — the
// r11-verified schedule. Chunk-XOR swizzle cs = c ^ ((row>>1)&3) both sides.
// bid/gx/nwg: block id within this GEMM's segment (nwg % 8 == 0 for the
// bijective XCD swizzle). OUT_MODE: 0 = fp32, 1 = bf16.
template <int KT, int OUT_MODE, bool HAS_BIAS>
DEVFN void gemm_body(const unsigned short* __restrict__ A,
                     const unsigned short* __restrict__ Bt,
                     void* __restrict__ Cv, const float* __restrict__ bias,
                     int ldc, int bid, int gx, int nwg,
                     unsigned short (*As)[128 * 32],
                     unsigned short (*Bs)[128 * 32]) {
  constexpr int K = KT * 32;

  const int t = threadIdx.x;
  const int wv = t >> 6, l = t & 63;
  const int wr = wv >> 1, wc = wv & 1;
  const int lr = l & 15, lk = l >> 4;

  const int swz = (bid & 7) * (nwg >> 3) + (bid >> 3);
  const int n0 = (swz % gx) * 128;
  const int m0 = (swz / gx) * 128;

  f32x4 acc[4][4];
#pragma unroll
  for (int m = 0; m < 4; ++m)
#pragma unroll
    for (int n = 0; n < 4; ++n) acc[m][n] = (f32x4){0.f, 0.f, 0.f, 0.f};

  const int wbase = (t & ~63) * 16;

  auto stage = [&](int buf, int k0) {
#pragma unroll
    for (int s = 0; s < 2; ++s) {
      const int cidx = s * 256 + t;
      const int row = cidx >> 2, c = cidx & 3;
      const int cs = c ^ ((row >> 1) & 3);
      gload16(A + (size_t)(m0 + row) * K + k0 + cs * 8,
              (char*)&As[buf][0] + (size_t)s * 4096 + wbase);
    }
#pragma unroll
    for (int s = 0; s < 2; ++s) {
      const int cidx = s * 256 + t;
      const int row = cidx >> 2, c = cidx & 3;
      const int cs = c ^ ((row >> 1) & 3);
      gload16(Bt + (size_t)(n0 + row) * K + k0 + cs * 8,
              (char*)&Bs[buf][0] + (size_t)s * 4096 + wbase);
    }
  };

  auto compute = [&](int buf) {
    short8v a[4], b[4];
#pragma unroll
    for (int m = 0; m < 4; ++m) {
      const int row = wr * 64 + m * 16 + lr;
      const int cs = lk ^ ((row >> 1) & 3);
      a[m] = *(const short8v*)&As[buf][row * 32 + cs * 8];
    }
#pragma unroll
    for (int n = 0; n < 4; ++n) {
      const int row = wc * 64 + n * 16 + lr;
      const int cs = lk ^ ((row >> 1) & 3);
      b[n] = *(const short8v*)&Bs[buf][row * 32 + cs * 8];
    }
#pragma unroll
    for (int m = 0; m < 4; ++m)
#pragma unroll
      for (int n = 0; n < 4; ++n)
        acc[m][n] = __builtin_amdgcn_mfma_f32_16x16x32_bf16(a[m], b[n], acc[m][n], 0, 0, 0);
  };

  stage(0, 0);
  if (KT > 1) stage(1, 32);

#pragma unroll
  for (int tt = 0; tt < KT; ++tt) {
    __builtin_amdgcn_s_barrier();        // B1: compute(tt-1) reads complete
    __builtin_amdgcn_sched_barrier(0);
    if (tt + 2 < KT) stage((tt + 2) % 3, (tt + 2) * 32);
    const int rem = (tt + 2 < KT ? tt + 2 : KT - 1) - tt;
    if (rem >= 2)      asm volatile("s_waitcnt vmcnt(8)" ::: "memory");
    else if (rem == 1) asm volatile("s_waitcnt vmcnt(4)" ::: "memory");
    else               asm volatile("s_waitcnt vmcnt(0)" ::: "memory");
    __builtin_amdgcn_s_barrier();        // B2: tile tt visible to all
    __builtin_amdgcn_sched_barrier(0);
    compute(tt % 3);
  }

#pragma unroll
  for (int m = 0; m < 4; ++m)
#pragma unroll
    for (int n = 0; n < 4; ++n) {
      const f32x4 v = acc[m][n];
      const int col = n0 + wc * 64 + n * 16 + lr;
      const int rbase = m0 + wr * 64 + m * 16 + lk * 4;
      float bv = 0.f;
      if (HAS_BIAS) bv = bias[col];
#pragma unroll
      for (int r = 0; r < 4; ++r) {
        const float val = v[r] + bv;
        if (OUT_MODE == 0) {
          ((float*)Cv)[(size_t)(rbase + r) * ldc + col] = val;
        } else {
          ((unsigned short*)Cv)[(size_t)(rbase + r) * ldc + col] = f2bf(val);
        }
      }
    }
}

// All three projection GEMMs (independent) in ONE dispatch:
// blocks [0,2048): KV (grid 4x512, ldc=512, planar K|V)
// blocks [2048,2176): Qf (grid 2x64)
// blocks [2176,2304): Gf (grid 2x64, K=64)
__global__ __launch_bounds__(256) void proj(
    const unsigned short* __restrict__ Abf, const unsigned short* __restrict__ Qbf,
    const unsigned short* __restrict__ Gbf,
    const unsigned short* __restrict__ Btkv, const unsigned short* __restrict__ Btq,
    const unsigned short* __restrict__ Btg,
    unsigned short* __restrict__ KV, unsigned short* __restrict__ Qf,
    unsigned short* __restrict__ Gf) {
  __shared__ unsigned short As[3][128 * 32];
  __shared__ unsigned short Bs[3][128 * 32];
  const int b = blockIdx.x;
  if (b < 2048) {
    gemm_body<8, 1, false>(Abf, Btkv, KV, nullptr, 512, b, 4, 2048, As, Bs);
  } else if (b < 2176) {
    gemm_body<8, 1, false>(Qbf, Btq, Qf, nullptr, 256, b - 2048, 2, 128, As, Bs);
  } else {
    gemm_body<2, 1, false>(Gbf, Btg, Gf, nullptr, 256, b - 2176, 2, 128, As, Bs);
  }
}

// Final: out = Opre @ Wo^T + bo (fp32 out).
__global__ __launch_bounds__(256) void gemm_final(
    const unsigned short* __restrict__ A, const unsigned short* __restrict__ Bt,
    void* __restrict__ C, const float* __restrict__ bias) {
  __shared__ unsigned short As[3][128 * 32];
  __shared__ unsigned short Bs[3][128 * 32];
  gemm_body<8, 0, true>(A, Bt, C, bias, 256, blockIdx.x, 2, 128, As, Bs);
}

// One block (256 thr) per query; 8 edge streams; 32 lanes per edge,
// 8 dims per lane; depth-2 rolling KV prefetch per stream.
// KV planar [N][512] = K|V. No online max (exact; scores bounded).
__global__ __launch_bounds__(256) void edge_attn(
    const int* __restrict__ s_idx, const int* __restrict__ q_start,
    const uint4* __restrict__ KV4, const unsigned short* __restrict__ Qf,
    const unsigned short* __restrict__ Gf, unsigned short* __restrict__ out_pre,
    const float* __restrict__ log_tau) {
  const int q = blockIdx.x;
  const int t = threadIdx.x;
  const int w = t >> 6;
  const int lane = t & 63;
  const int stream = w * 2 + (lane >> 5);
  const int sl = lane & 31;
  const int start = q_start[q], end = q_start[q + 1];

  const float tau = __expf(log_tau[0]);
  const float rs = 1.0f / (5.656854249492381f * tau);

  float qv[8];
  {
    uint4 qw = *(const uint4*)(Qf + (size_t)q * 256 + sl * 8);
    const unsigned int ws_[4] = {qw.x, qw.y, qw.z, qw.w};
#pragma unroll
    for (int j = 0; j < 4; ++j) {
      qv[2 * j]     = bf2f((unsigned short)(ws_[j] & 0xffffu)) * rs;
      qv[2 * j + 1] = bf2f((unsigned short)(ws_[j] >> 16)) * rs;
    }
  }

  float o[8];
#pragma unroll
  for (int j = 0; j < 8; ++j) o[j] = 0.f;
  float lsum_p = 0.f;

  __shared__ int sseg[1024];

  for (int cb = start; cb < end; cb += 1024) {
    const int nb = min(1024, end - cb);
    __syncthreads();
    for (int jj = t; jj < nb; jj += 256) sseg[jj] = s_idx[cb + jj];
    __syncthreads();

    int j = stream;
    uint4 kc = {}, vc = {}, kn = {}, vn = {};
    if (j < nb) {
      const uint4* bp = KV4 + (size_t)sseg[j] * 64;
      kc = bp[sl];
      vc = bp[32 + sl];
    }
    if (j + 8 < nb) {
      const uint4* bp = KV4 + (size_t)sseg[j + 8] * 64;
      kn = bp[sl];
      vn = bp[32 + sl];
    }
    while (j < nb) {
      const int j2 = j + 16;
      uint4 k2 = {}, v2 = {};
      if (j2 < nb) {
        const uint4* bp = KV4 + (size_t)sseg[j2] * 64;
        k2 = bp[sl];
        v2 = bp[32 + sl];
      }
      const unsigned int kw[4] = {kc.x, kc.y, kc.z, kc.w};
      float p = 0.f;
#pragma unroll
      for (int jj = 0; jj < 4; ++jj) {
        p = fmaf(qv[2 * jj], bf2f((unsigned short)(kw[jj] & 0xffffu)), p);
        p = fmaf(qv[2 * jj + 1], bf2f((unsigned short)(kw[jj] >> 16)), p);
      }
      p += __shfl_xor(p, 1);
      p += __shfl_xor(p, 2);
      const float ew = __expf(p);
      lsum_p += ew;
      const unsigned int vw[4] = {vc.x, vc.y, vc.z, vc.w};
#pragma unroll
      for (int jj = 0; jj < 4; ++jj) {
        o[2 * jj]     = fmaf(ew, bf2f((unsigned short)(vw[jj] & 0xffffu)), o[2 * jj]);
        o[2 * jj + 1] = fmaf(ew, bf2f((unsigned short)(vw[jj] >> 16)), o[2 * jj + 1]);
      }
      j += 8;
      kc = kn; vc = vn;
      kn = k2; vn = v2;
    }
  }

  __shared__ float o_sh[8][256];
  __shared__ float l_sh[8][8];
  *(float4*)&o_sh[stream][sl * 8]     = (float4){o[0], o[1], o[2], o[3]};
  *(float4*)&o_sh[stream][sl * 8 + 4] = (float4){o[4], o[5], o[6], o[7]};
  if ((sl & 3) == 0) l_sh[stream][sl >> 2] = lsum_p;
  __syncthreads();

  float osum = 0.f, lsum = 0.f;
  const int h = t >> 5;
#pragma unroll
  for (int s = 0; s < 8; ++s) {
    osum += o_sh[s][t];
    lsum += l_sh[s][h];
  }
  const float inv = 1.0f / fmaxf(lsum, 1e-8f);
  float res = 0.f;
  if (end > start) res = osum * inv + (lsum * inv) * bf2f(Gf[(size_t)q * 256 + t]);
  out_pre[(size_t)q * 256 + t] = f2bf(res);
}

extern "C" void kernel_launch(void* const* d_in, const int* in_sizes, int n_in,
                              void* d_out, int out_size, void* d_ws, size_t ws_size,
                              hipStream_t stream) {
  const float* query   = (const float*)d_in[0];
  const float* support = (const float*)d_in[1];
  const float* geo     = (const float*)d_in[2];
  const int*   q_idx   = (const int*)d_in[3];
  const int*   s_idx   = (const int*)d_in[4];
  const float* Wq      = (const float*)d_in[6];
  const float* Wk      = (const float*)d_in[7];
  const float* Wv      = (const float*)d_in[8];
  const float* Wg      = (const float*)d_in[9];
  const float* Wo      = (const float*)d_in[10];
  const float* bo      = (const float*)d_in[11];
  const float* log_tau = (const float*)d_in[12];

  const int D = 256;
  const int Q = in_sizes[0] / D;   // 8192
  const int N = in_sizes[1] / D;   // 65536
  const int E = in_sizes[3];       // 262144

  unsigned short* ws = (unsigned short*)d_ws;
  unsigned short* KV   = ws;                       // [N][512] bf16 planar K|V
  unsigned short* Abf  = KV   + (size_t)N * 512;   // support bf16 [N][256]
  unsigned short* Qbf  = Abf  + (size_t)N * 256;   // query bf16 [Q][256]
  unsigned short* Gbf  = Qbf  + (size_t)Q * 256;   // geo bf16 [Q][64]
  unsigned short* Qf   = Gbf  + (size_t)Q * 64;    // bf16 [Q][256]
  unsigned short* Gf   = Qf   + (size_t)Q * 256;   // bf16 [Q][256]
  unsigned short* Opre = Gf   + (size_t)Q * 256;   // bf16 [Q][256]
  unsigned short* Btkv = Opre + (size_t)Q * 256;   // [512][256] = [Wk^T; Wv^T]
  unsigned short* Btq  = Btkv + 512 * 256;         // [256][256]
  unsigned short* Btg  = Btq  + 256 * 256;         // [256][64]
  unsigned short* Bto  = Btg  + 256 * 64;          // [256][256]
  int* q_start = (int*)(Bto + 256 * 256);          // [Q+1]

  dim3 blk(256);

  prep<<<dim3(2993), blk, 0, stream>>>(
      support, query, geo, Wk, Wv, Wq, Wo, Wg,
      Abf, Qbf, Gbf, Btkv, Btq, Bto, Btg, q_idx, q_start, N, Q, E);

  // KV + Qf + Gf projections in one dispatch
  proj<<<dim3(2304), blk, 0, stream>>>(Abf, Qbf, Gbf, Btkv, Btq, Btg,
                                       KV, Qf, Gf);

  edge_attn<<<dim3(Q), blk, 0, stream>>>(s_idx, q_start, (const uint4*)KV,
                                         Qf, Gf, Opre, log_tau);

  gemm_final<<<dim3(128), blk, 0, stream>>>(Opre, Bto, d_out, bo);
}

// Round 14
// 98.647 us; speedup vs baseline: 1.3795x; 1.0396x over previous
//
#include <hip/hip_runtime.h>
#include <hip/hip_bf16.h>
#include <hip/hip_fp8.h>

typedef __attribute__((ext_vector_type(8))) short short8v;
typedef __attribute__((ext_vector_type(4))) float f32x4;
typedef __attribute__((ext_vector_type(2))) float f32x2;

#define DEVFN __device__ __forceinline__

DEVFN unsigned short f2bf(float x) {
  __hip_bfloat16 h = __float2bfloat16(x);
  return *reinterpret_cast<unsigned short*>(&h);
}

DEVFN float bf2f(unsigned short u) {
  unsigned int x = ((unsigned int)u) << 16;
  float f;
  __builtin_memcpy(&f, &x, 4);
  return f;
}

DEVFN unsigned char f2fp8(float x) {
  __hip_fp8_e4m3 h(x);
  return *reinterpret_cast<unsigned char*>(&h);
}

#if __has_builtin(__builtin_amdgcn_cvt_pk_f32_fp8)
DEVFN void fp8x4_to_f32(unsigned int u, float* out) {
  f32x2 lo = __builtin_amdgcn_cvt_pk_f32_fp8(u, false);
  f32x2 hi = __builtin_amdgcn_cvt_pk_f32_fp8(u, true);
  out[0] = lo[0]; out[1] = lo[1]; out[2] = hi[0]; out[3] = hi[1];
}
#else
DEVFN float fp8_1_to_f32(unsigned int b) {
  const unsigned int s = (b >> 7) & 1, e = (b >> 3) & 15, m = b & 7;
  unsigned int bits = (s << 31) | ((e + 120) << 23) | (m << 20);
  float f;
  __builtin_memcpy(&f, &bits, 4);
  if (e == 0) f = (s ? -1.f : 1.f) * (float)m * 0.001953125f;  // 2^-9 subnormal
  return f;
}
DEVFN void fp8x4_to_f32(unsigned int u, float* out) {
  out[0] = fp8_1_to_f32(u & 0xff);
  out[1] = fp8_1_to_f32((u >> 8) & 0xff);
  out[2] = fp8_1_to_f32((u >> 16) & 0xff);
  out[3] = fp8_1_to_f32((u >> 24) & 0xff);
}
#endif

DEVFN void gload16(const void* g, void* l) {
  __builtin_amdgcn_global_load_lds(
      (const __attribute__((address_space(1))) void*)g,
      (__attribute__((address_space(3))) void*)l, 16, 0, 0);
}

// All preprocessing: bf16 casts of support/query/geo, weight transpose-casts,
// q_start binary search.
__global__ __launch_bounds__(256) void prep(
    const float* __restrict__ support, const float* __restrict__ query,
    const float* __restrict__ geo,
    const float* __restrict__ Wk, const float* __restrict__ Wv,
    const float* __restrict__ Wq, const float* __restrict__ Wo,
    const float* __restrict__ Wg,
    unsigned short* __restrict__ Abf, unsigned short* __restrict__ Qbf,
    unsigned short* __restrict__ Gbf,
    unsigned short* __restrict__ Btkv, unsigned short* __restrict__ Btq,
    unsigned short* __restrict__ Bto, unsigned short* __restrict__ Btg,
    const int* __restrict__ q_idx, int* __restrict__ q_start,
    int N, int Q, int E) {
  const int b = blockIdx.x, t = threadIdx.x;
  if (b < 2048) {                       // support cast: N*64 float4s
    const int n4 = N * 64;
    for (int i = b * 256 + t; i < n4; i += 2048 * 256) {
      float4 v = ((const float4*)support)[i];
      ushort4 o = {f2bf(v.x), f2bf(v.y), f2bf(v.z), f2bf(v.w)};
      ((ushort4*)Abf)[i] = o;
    }
  } else if (b < 2560) {                // query cast: Q*64 float4s
    const int n4 = Q * 64;
    for (int i = (b - 2048) * 256 + t; i < n4; i += 512 * 256) {
      float4 v = ((const float4*)query)[i];
      ushort4 o = {f2bf(v.x), f2bf(v.y), f2bf(v.z), f2bf(v.w)};
      ((ushort4*)Qbf)[i] = o;
    }
  } else if (b < 2688) {                // geo cast: Q*16 float4s
    const int n4 = Q * 16;
    for (int i = (b - 2560) * 256 + t; i < n4; i += 128 * 256) {
      float4 v = ((const float4*)geo)[i];
      ushort4 o = {f2bf(v.x), f2bf(v.y), f2bf(v.z), f2bf(v.w)};
      ((ushort4*)Gbf)[i] = o;
    }
  } else if (b < 2944) {                // Wk/Wv/Wq/Wo transpose-cast
    const int wi = (b - 2688) >> 6, bb = (b - 2688) & 63;
    const float* W = (wi == 0) ? Wk : (wi == 1) ? Wv : (wi == 2) ? Wq : Wo;
    unsigned short* O = (wi == 0) ? Btkv : (wi == 1) ? (Btkv + 65536)
                     : (wi == 2) ? Btq : Bto;
    for (int id = bb * 256 + t; id < 65536; id += 64 * 256) {
      const int n = id >> 8, k = id & 255;
      O[id] = f2bf(W[k * 256 + n]);
    }
  } else if (b < 2960) {                // Wg [64][256] -> Btg [256][64]
    for (int id = (b - 2944) * 256 + t; id < 16384; id += 16 * 256) {
      const int n = id >> 6, k = id & 63;
      Btg[id] = f2bf(Wg[k * 256 + n]);
    }
  } else {                              // q_start
    const int q = (b - 2960) * 256 + t;
    if (q <= Q) {
      int lo = 0, hi = E;
      while (lo < hi) { int mid = (lo + hi) >> 1; if (q_idx[mid] < q) lo = mid + 1; else hi = mid; }
      q_start[q] = lo;
    }
  }
}

// Deep-pipelined GEMM body (r11-verified schedule): 3 LDS buffers, depth-2
// prefetch, counted vmcnt. OUT_MODE: 0 = fp32, 1 = bf16,
// 2 = KV row (768 B): col<256 -> fp8 e4m3 at row*768+col,
//                     col>=256 -> bf16 at row*768+256+(col-256)*2.
template <int KT, int OUT_MODE, bool HAS_BIAS>
DEVFN void gemm_body(const unsigned short* __restrict__ A,
                     const unsigned short* __restrict__ Bt,
                     void* __restrict__ Cv, const float* __restrict__ bias,
                     int ldc, int bid, int gx, int nwg,
                     unsigned short (*As)[128 * 32],
                     unsigned short (*Bs)[128 * 32]) {
  constexpr int K = KT * 32;

  const int t = threadIdx.x;
  const int wv = t >> 6, l = t & 63;
  const int wr = wv >> 1, wc = wv & 1;
  const int lr = l & 15, lk = l >> 4;

  const int swz = (bid & 7) * (nwg >> 3) + (bid >> 3);
  const int n0 = (swz % gx) * 128;
  const int m0 = (swz / gx) * 128;

  f32x4 acc[4][4];
#pragma unroll
  for (int m = 0; m < 4; ++m)
#pragma unroll
    for (int n = 0; n < 4; ++n) acc[m][n] = (f32x4){0.f, 0.f, 0.f, 0.f};

  const int wbase = (t & ~63) * 16;

  auto stage = [&](int buf, int k0) {
#pragma unroll
    for (int s = 0; s < 2; ++s) {
      const int cidx = s * 256 + t;
      const int row = cidx >> 2, c = cidx & 3;
      const int cs = c ^ ((row >> 1) & 3);
      gload16(A + (size_t)(m0 + row) * K + k0 + cs * 8,
              (char*)&As[buf][0] + (size_t)s * 4096 + wbase);
    }
#pragma unroll
    for (int s = 0; s < 2; ++s) {
      const int cidx = s * 256 + t;
      const int row = cidx >> 2, c = cidx & 3;
      const int cs = c ^ ((row >> 1) & 3);
      gload16(Bt + (size_t)(n0 + row) * K + k0 + cs * 8,
              (char*)&Bs[buf][0] + (size_t)s * 4096 + wbase);
    }
  };

  auto compute = [&](int buf) {
    short8v a[4], b[4];
#pragma unroll
    for (int m = 0; m < 4; ++m) {
      const int row = wr * 64 + m * 16 + lr;
      const int cs = lk ^ ((row >> 1) & 3);
      a[m] = *(const short8v*)&As[buf][row * 32 + cs * 8];
    }
#pragma unroll
    for (int n = 0; n < 4; ++n) {
      const int row = wc * 64 + n * 16 + lr;
      const int cs = lk ^ ((row >> 1) & 3);
      b[n] = *(const short8v*)&Bs[buf][row * 32 + cs * 8];
    }
#pragma unroll
    for (int m = 0; m < 4; ++m)
#pragma unroll
      for (int n = 0; n < 4; ++n)
        acc[m][n] = __builtin_amdgcn_mfma_f32_16x16x32_bf16(a[m], b[n], acc[m][n], 0, 0, 0);
  };

  stage(0, 0);
  if (KT > 1) stage(1, 32);

#pragma unroll
  for (int tt = 0; tt < KT; ++tt) {
    __builtin_amdgcn_s_barrier();        // B1: compute(tt-1) reads complete
    __builtin_amdgcn_sched_barrier(0);
    if (tt + 2 < KT) stage((tt + 2) % 3, (tt + 2) * 32);
    const int rem = (tt + 2 < KT ? tt + 2 : KT - 1) - tt;
    if (rem >= 2)      asm volatile("s_waitcnt vmcnt(8)" ::: "memory");
    else if (rem == 1) asm volatile("s_waitcnt vmcnt(4)" ::: "memory");
    else               asm volatile("s_waitcnt vmcnt(0)" ::: "memory");
    __builtin_amdgcn_s_barrier();        // B2: tile tt visible to all
    __builtin_amdgcn_sched_barrier(0);
    compute(tt % 3);
  }

#pragma unroll
  for (int m = 0; m < 4; ++m)
#pragma unroll
    for (int n = 0; n < 4; ++n) {
      const f32x4 v = acc[m][n];
      const int col = n0 + wc * 64 + n * 16 + lr;
      const int rbase = m0 + wr * 64 + m * 16 + lk * 4;
      float bv = 0.f;
      if (HAS_BIAS) bv = bias[col];
#pragma unroll
      for (int r = 0; r < 4; ++r) {
        const float val = v[r] + bv;
        if (OUT_MODE == 0) {
          ((float*)Cv)[(size_t)(rbase + r) * ldc + col] = val;
        } else if (OUT_MODE == 1) {
          ((unsigned short*)Cv)[(size_t)(rbase + r) * ldc + col] = f2bf(val);
        } else {
          unsigned char* Cb = (unsigned char*)Cv;
          const size_t rb = (size_t)(rbase + r) * 768;
          if (col < 256) {
            Cb[rb + col] = f2fp8(val);
          } else {
            *(unsigned short*)(Cb + rb + 256 + (size_t)(col - 256) * 2) = f2bf(val);
          }
        }
      }
    }
}

// All three projection GEMMs (independent) in ONE dispatch:
// blocks [0,2048): KV (grid 4x512, OUT_MODE=2: fp8 K | bf16 V, 768 B rows)
// blocks [2048,2176): Qf (grid 2x64)
// blocks [2176,2304): Gf (grid 2x64, K=64)
__global__ __launch_bounds__(256) void proj(
    const unsigned short* __restrict__ Abf, const unsigned short* __restrict__ Qbf,
    const unsigned short* __restrict__ Gbf,
    const unsigned short* __restrict__ Btkv, const unsigned short* __restrict__ Btq,
    const unsigned short* __restrict__ Btg,
    unsigned char* __restrict__ KV, unsigned short* __restrict__ Qf,
    unsigned short* __restrict__ Gf) {
  __shared__ unsigned short As[3][128 * 32];
  __shared__ unsigned short Bs[3][128 * 32];
  const int b = blockIdx.x;
  if (b < 2048) {
    gemm_body<8, 2, false>(Abf, Btkv, KV, nullptr, 0, b, 4, 2048, As, Bs);
  } else if (b < 2176) {
    gemm_body<8, 1, false>(Qbf, Btq, Qf, nullptr, 256, b - 2048, 2, 128, As, Bs);
  } else {
    gemm_body<2, 1, false>(Gbf, Btg, Gf, nullptr, 256, b - 2176, 2, 128, As, Bs);
  }
}

// Final: out = Opre @ Wo^T + bo (fp32 out).
__global__ __launch_bounds__(256) void gemm_final(
    const unsigned short* __restrict__ A, const unsigned short* __restrict__ Bt,
    void* __restrict__ C, const float* __restrict__ bias) {
  __shared__ unsigned short As[3][128 * 32];
  __shared__ unsigned short Bs[3][128 * 32];
  gemm_body<8, 0, true>(A, Bt, C, bias, 256, blockIdx.x, 2, 128, As, Bs);
}

// One block (256 thr) per query; 8 edge streams; 32 lanes per edge.
// KV row (768 B) = K fp8 e4m3 (256 B) | V bf16 (512 B). Per lane: K uint2
// (8 fp8 = 8 dims), V uint4 (8 bf16). Depth-2 rolling prefetch per stream.
// No online max (exact; scores bounded).
__global__ __launch_bounds__(256) void edge_attn(
    const int* __restrict__ s_idx, const int* __restrict__ q_start,
    const unsigned char* __restrict__ KVb, const unsigned short* __restrict__ Qf,
    const unsigned short* __restrict__ Gf, unsigned short* __restrict__ out_pre,
    const float* __restrict__ log_tau) {
  const int q = blockIdx.x;
  const int t = threadIdx.x;
  const int w = t >> 6;
  const int lane = t & 63;
  const int stream = w * 2 + (lane >> 5);
  const int sl = lane & 31;
  const int start = q_start[q], end = q_start[q + 1];

  const float tau = __expf(log_tau[0]);
  const float rs = 1.0f / (5.656854249492381f * tau);

  float qv[8];
  {
    uint4 qw = *(const uint4*)(Qf + (size_t)q * 256 + sl * 8);
    const unsigned int ws_[4] = {qw.x, qw.y, qw.z, qw.w};
#pragma unroll
    for (int j = 0; j < 4; ++j) {
      qv[2 * j]     = bf2f((unsigned short)(ws_[j] & 0xffffu)) * rs;
      qv[2 * j + 1] = bf2f((unsigned short)(ws_[j] >> 16)) * rs;
    }
  }

  float o[8];
#pragma unroll
  for (int j = 0; j < 8; ++j) o[j] = 0.f;
  float lsum_p = 0.f;

  __shared__ int sseg[1024];

  for (int cb = start; cb < end; cb += 1024) {
    const int nb = min(1024, end - cb);
    __syncthreads();
    for (int jj = t; jj < nb; jj += 256) sseg[jj] = s_idx[cb + jj];
    __syncthreads();

    int j = stream;
    uint2 kc = {}, kn = {};
    uint4 vc = {}, vn = {};
    if (j < nb) {
      const unsigned char* bp = KVb + (size_t)sseg[j] * 768;
      kc = *(const uint2*)(bp + sl * 8);
      vc = *(const uint4*)(bp + 256 + sl * 16);
    }
    if (j + 8 < nb) {
      const unsigned char* bp = KVb + (size_t)sseg[j + 8] * 768;
      kn = *(const uint2*)(bp + sl * 8);
      vn = *(const uint4*)(bp + 256 + sl * 16);
    }
    while (j < nb) {
      const int j2 = j + 16;
      uint2 k2 = {};
      uint4 v2 = {};
      if (j2 < nb) {
        const unsigned char* bp = KVb + (size_t)sseg[j2] * 768;
        k2 = *(const uint2*)(bp + sl * 8);
        v2 = *(const uint4*)(bp + 256 + sl * 16);
      }
      float kf[8];
      fp8x4_to_f32(kc.x, kf);
      fp8x4_to_f32(kc.y, kf + 4);
      float p = 0.f;
#pragma unroll
      for (int jj = 0; jj < 8; ++jj) p = fmaf(qv[jj], kf[jj], p);
      p += __shfl_xor(p, 1);
      p += __shfl_xor(p, 2);
      const float ew = __expf(p);
      lsum_p += ew;
      const unsigned int vw[4] = {vc.x, vc.y, vc.z, vc.w};
#pragma unroll
      for (int jj = 0; jj < 4; ++jj) {
        o[2 * jj]     = fmaf(ew, bf2f((unsigned short)(vw[jj] & 0xffffu)), o[2 * jj]);
        o[2 * jj + 1] = fmaf(ew, bf2f((unsigned short)(vw[jj] >> 16)), o[2 * jj + 1]);
      }
      j += 8;
      kc = kn; vc = vn;
      kn = k2; vn = v2;
    }
  }

  __shared__ float o_sh[8][256];
  __shared__ float l_sh[8][8];
  *(float4*)&o_sh[stream][sl * 8]     = (float4){o[0], o[1], o[2], o[3]};
  *(float4*)&o_sh[stream][sl * 8 + 4] = (float4){o[4], o[5], o[6], o[7]};
  if ((sl & 3) == 0) l_sh[stream][sl >> 2] = lsum_p;
  __syncthreads();

  float osum = 0.f, lsum = 0.f;
  const int h = t >> 5;
#pragma unroll
  for (int s = 0; s < 8; ++s) {
    osum += o_sh[s][t];
    lsum += l_sh[s][h];
  }
  const float inv = 1.0f / fmaxf(lsum, 1e-8f);
  float res = 0.f;
  if (end > start) res = osum * inv + (lsum * inv) * bf2f(Gf[(size_t)q * 256 + t]);
  out_pre[(size_t)q * 256 + t] = f2bf(res);
}

extern "C" void kernel_launch(void* const* d_in, const int* in_sizes, int n_in,
                              void* d_out, int out_size, void* d_ws, size_t ws_size,
                              hipStream_t stream) {
  const float* query   = (const float*)d_in[0];
  const float* support = (const float*)d_in[1];
  const float* geo     = (const float*)d_in[2];
  const int*   q_idx   = (const int*)d_in[3];
  const int*   s_idx   = (const int*)d_in[4];
  const float* Wq      = (const float*)d_in[6];
  const float* Wk      = (const float*)d_in[7];
  const float* Wv      = (const float*)d_in[8];
  const float* Wg      = (const float*)d_in[9];
  const float* Wo      = (const float*)d_in[10];
  const float* bo      = (const float*)d_in[11];
  const float* log_tau = (const float*)d_in[12];

  const int D = 256;
  const int Q = in_sizes[0] / D;   // 8192
  const int N = in_sizes[1] / D;   // 65536
  const int E = in_sizes[3];       // 262144

  unsigned char* wsb = (unsigned char*)d_ws;
  unsigned char*  KV   = wsb;                                  // [N][768] fp8 K | bf16 V
  unsigned short* Abf  = (unsigned short*)(wsb + (size_t)N * 768);  // [N][256]
  unsigned short* Qbf  = Abf  + (size_t)N * 256;   // [Q][256]
  unsigned short* Gbf  = Qbf  + (size_t)Q * 256;   // [Q][64]
  unsigned short* Qf   = Gbf  + (size_t)Q * 64;    // [Q][256]
  unsigned short* Gf   = Qf   + (size_t)Q * 256;   // [Q][256]
  unsigned short* Opre = Gf   + (size_t)Q * 256;   // [Q][256]
  unsigned short* Btkv = Opre + (size_t)Q * 256;   // [512][256] = [Wk^T; Wv^T]
  unsigned short* Btq  = Btkv + 512 * 256;         // [256][256]
  unsigned short* Btg  = Btq  + 256 * 256;         // [256][64]
  unsigned short* Bto  = Btg  + 256 * 64;          // [256][256]
  int* q_start = (int*)(Bto + 256 * 256);          // [Q+1]

  dim3 blk(256);

  prep<<<dim3(2993), blk, 0, stream>>>(
      support, query, geo, Wk, Wv, Wq, Wo, Wg,
      Abf, Qbf, Gbf, Btkv, Btq, Bto, Btg, q_idx, q_start, N, Q, E);

  // KV + Qf + Gf projections in one dispatch
  proj<<<dim3(2304), blk, 0, stream>>>(Abf, Qbf, Gbf, Btkv, Btq, Btg,
                                       KV, Qf, Gf);

  edge_attn<<<dim3(Q), blk, 0, stream>>>(s_idx, q_start, KV,
                                         Qf, Gf, Opre, log_tau);

  gemm_final<<<dim3(128), blk, 0, stream>>>(Opre, Bto, d_out, bo);
}

// Round 15
// 93.561 us; speedup vs baseline: 1.4545x; 1.0544x over previous
//
#include <hip/hip_runtime.h>
#include <hip/hip_bf16.h>
#include <hip/hip_fp8.h>

typedef __attribute__((ext_vector_type(8))) short short8v;
typedef __attribute__((ext_vector_type(4))) float f32x4;
typedef __attribute__((ext_vector_type(2))) float f32x2;

#define DEVFN __device__ __forceinline__

DEVFN unsigned short f2bf(float x) {
  __hip_bfloat16 h = __float2bfloat16(x);
  return *reinterpret_cast<unsigned short*>(&h);
}

DEVFN float bf2f(unsigned short u) {
  unsigned int x = ((unsigned int)u) << 16;
  float f;
  __builtin_memcpy(&f, &x, 4);
  return f;
}

DEVFN unsigned char f2fp8(float x) {
  __hip_fp8_e4m3 h(x);
  return *reinterpret_cast<unsigned char*>(&h);
}

#if __has_builtin(__builtin_amdgcn_cvt_pk_f32_fp8)
DEVFN void fp8x4_to_f32(unsigned int u, float* out) {
  f32x2 lo = __builtin_amdgcn_cvt_pk_f32_fp8(u, false);
  f32x2 hi = __builtin_amdgcn_cvt_pk_f32_fp8(u, true);
  out[0] = lo[0]; out[1] = lo[1]; out[2] = hi[0]; out[3] = hi[1];
}
#else
DEVFN float fp8_1_to_f32(unsigned int b) {
  const unsigned int s = (b >> 7) & 1, e = (b >> 3) & 15, m = b & 7;
  unsigned int bits = (s << 31) | ((e + 120) << 23) | (m << 20);
  float f;
  __builtin_memcpy(&f, &bits, 4);
  if (e == 0) f = (s ? -1.f : 1.f) * (float)m * 0.001953125f;
  return f;
}
DEVFN void fp8x4_to_f32(unsigned int u, float* out) {
  out[0] = fp8_1_to_f32(u & 0xff);
  out[1] = fp8_1_to_f32((u >> 8) & 0xff);
  out[2] = fp8_1_to_f32((u >> 16) & 0xff);
  out[3] = fp8_1_to_f32((u >> 24) & 0xff);
}
#endif

DEVFN void gload16(const void* g, void* l) {
  __builtin_amdgcn_global_load_lds(
      (const __attribute__((address_space(1))) void*)g,
      (__attribute__((address_space(3))) void*)l, 16, 0, 0);
}

// Weight transpose-casts + q_start only (input casts fused into proj).
__global__ __launch_bounds__(256) void prep(
    const float* __restrict__ Wk, const float* __restrict__ Wv,
    const float* __restrict__ Wq, const float* __restrict__ Wo,
    const float* __restrict__ Wg,
    unsigned short* __restrict__ Btkv, unsigned short* __restrict__ Btq,
    unsigned short* __restrict__ Bto, unsigned short* __restrict__ Btg,
    const int* __restrict__ q_idx, int* __restrict__ q_start, int Q, int E) {
  const int b = blockIdx.x, t = threadIdx.x;
  if (b < 256) {
    const int wi = b >> 6, bb = b & 63;
    const float* W = (wi == 0) ? Wk : (wi == 1) ? Wv : (wi == 2) ? Wq : Wo;
    unsigned short* O = (wi == 0) ? Btkv : (wi == 1) ? (Btkv + 65536)
                     : (wi == 2) ? Btq : Bto;
    for (int id = bb * 256 + t; id < 65536; id += 64 * 256) {
      const int n = id >> 8, k = id & 255;
      O[id] = f2bf(W[k * 256 + n]);
    }
  } else if (b < 272) {
    for (int id = (b - 256) * 256 + t; id < 16384; id += 16 * 256) {
      const int n = id >> 6, k = id & 63;
      Btg[id] = f2bf(Wg[k * 256 + n]);
    }
  } else {
    const int q = (b - 272) * 256 + t;
    if (q <= Q) {
      int lo = 0, hi = E;
      while (lo < hi) { int mid = (lo + hi) >> 1; if (q_idx[mid] < q) lo = mid + 1; else hi = mid; }
      q_start[q] = lo;
    }
  }
}

// Deep-pipelined GEMM body (r11 schedule: 3 LDS buffers, depth-2 prefetch,
// counted vmcnt). A either bf16 [M][K] via global_load_lds, or fp32 [M][K]
// reg-staged (load float4x4 -> cvt once -> swizzled ds_write_b128; slot rule:
// tile T lives in reg-slot T&1, written to LDS one iter after load).
// OUT_MODE: 0 = fp32, 1 = bf16 at row*ldc+col,
// 2 = KV row (768 B): col<256 -> fp8 e4m3; col>=256 -> bf16.
template <int KT, bool A_F32, int OUT_MODE, bool HAS_BIAS>
DEVFN void gemm_body(const void* __restrict__ Av,
                     const unsigned short* __restrict__ Bt,
                     void* __restrict__ Cv, const float* __restrict__ bias,
                     int ldc, int bid, int gx, int nwg,
                     unsigned short (*As)[128 * 32],
                     unsigned short (*Bs)[128 * 32]) {
  constexpr int K = KT * 32;

  const int t = threadIdx.x;
  const int wv = t >> 6, l = t & 63;
  const int wr = wv >> 1, wc = wv & 1;
  const int lr = l & 15, lk = l >> 4;

  const int swz = (bid & 7) * (nwg >> 3) + (bid >> 3);
  const int n0 = (swz % gx) * 128;
  const int m0 = (swz / gx) * 128;

  f32x4 acc[4][4];
#pragma unroll
  for (int m = 0; m < 4; ++m)
#pragma unroll
    for (int n = 0; n < 4; ++n) acc[m][n] = (f32x4){0.f, 0.f, 0.f, 0.f};

  const int wbase = (t & ~63) * 16;

  // fp32 A reg-staging geometry (r7-verified, 0 LDS conflicts)
  const int arow = t >> 1, ac0 = (t & 1) * 2;
  const float* Afp = A_F32 ? ((const float*)Av + (size_t)(m0 + arow) * K + ac0 * 8)
                           : nullptr;
  float4 reg0[4], reg1[4];

  auto loadA = [&](float4 (&rg)[4], int k0) {
    const float* p = Afp + k0;
#pragma unroll
    for (int j = 0; j < 4; ++j) rg[j] = *(const float4*)(p + j * 4);
  };
  auto writeA = [&](float4 (&rg)[4], int buf) {
    unsigned short u[16];
#pragma unroll
    for (int j = 0; j < 4; ++j) {
      u[4 * j + 0] = f2bf(rg[j].x); u[4 * j + 1] = f2bf(rg[j].y);
      u[4 * j + 2] = f2bf(rg[j].z); u[4 * j + 3] = f2bf(rg[j].w);
    }
    const int cs0 = ac0 ^ ((arow >> 1) & 3);
    const int cs1 = (ac0 + 1) ^ ((arow >> 1) & 3);
    *(short8v*)&As[buf][arow * 32 + cs0 * 8] = *(short8v*)&u[0];
    *(short8v*)&As[buf][arow * 32 + cs1 * 8] = *(short8v*)&u[8];
  };
  auto stageA_lds = [&](int buf, int k0) {
    const unsigned short* Ab = (const unsigned short*)Av;
#pragma unroll
    for (int s = 0; s < 2; ++s) {
      const int cidx = s * 256 + t;
      const int row = cidx >> 2, c = cidx & 3;
      const int cs = c ^ ((row >> 1) & 3);
      gload16(Ab + (size_t)(m0 + row) * K + k0 + cs * 8,
              (char*)&As[buf][0] + (size_t)s * 4096 + wbase);
    }
  };
  auto stageB = [&](int buf, int k0) {
#pragma unroll
    for (int s = 0; s < 2; ++s) {
      const int cidx = s * 256 + t;
      const int row = cidx >> 2, c = cidx & 3;
      const int cs = c ^ ((row >> 1) & 3);
      gload16(Bt + (size_t)(n0 + row) * K + k0 + cs * 8,
              (char*)&Bs[buf][0] + (size_t)s * 4096 + wbase);
    }
  };

  auto compute = [&](int buf) {
    short8v a[4], b[4];
#pragma unroll
    for (int m = 0; m < 4; ++m) {
      const int row = wr * 64 + m * 16 + lr;
      const int cs = lk ^ ((row >> 1) & 3);
      a[m] = *(const short8v*)&As[buf][row * 32 + cs * 8];
    }
#pragma unroll
    for (int n = 0; n < 4; ++n) {
      const int row = wc * 64 + n * 16 + lr;
      const int cs = lk ^ ((row >> 1) & 3);
      b[n] = *(const short8v*)&Bs[buf][row * 32 + cs * 8];
    }
#pragma unroll
    for (int m = 0; m < 4; ++m)
#pragma unroll
      for (int n = 0; n < 4; ++n)
        acc[m][n] = __builtin_amdgcn_mfma_f32_16x16x32_bf16(a[m], b[n], acc[m][n], 0, 0, 0);
  };

  // prologue: B first (so implicit A-reg waits also cover older B tiles)
  stageB(0, 0);
  if (KT > 1) stageB(1, 32);
  if (A_F32) {
    loadA(reg0, 0);                      // tile 0 -> slot 0
    if (KT > 1) loadA(reg1, 32);         // tile 1 -> slot 1
    writeA(reg0, 0);                     // As[0] (compiler waits tile0 loads)
  } else {
    stageA_lds(0, 0);
    if (KT > 1) stageA_lds(1, 32);
  }

#pragma unroll
  for (int tt = 0; tt < KT; ++tt) {
    __builtin_amdgcn_s_barrier();        // B1: compute(tt-1) done everywhere
    __builtin_amdgcn_sched_barrier(0);
    if (A_F32) {
      if (tt + 2 < KT) {
        if (((tt + 2) & 1) == 0) loadA(reg0, (tt + 2) * 32);
        else                     loadA(reg1, (tt + 2) * 32);
        stageB((tt + 2) % 3, (tt + 2) * 32);
      }
      if (tt + 1 < KT) {
        if (((tt + 1) & 1) == 0) writeA(reg0, (tt + 1) % 3);
        else                     writeA(reg1, (tt + 1) % 3);
      }
      if (tt < KT - 2)       asm volatile("s_waitcnt vmcnt(8) lgkmcnt(0)" ::: "memory");
      else if (tt == KT - 2) asm volatile("s_waitcnt vmcnt(2) lgkmcnt(0)" ::: "memory");
      else                   asm volatile("s_waitcnt vmcnt(0) lgkmcnt(0)" ::: "memory");
    } else {
      if (tt + 2 < KT) {
        stageA_lds((tt + 2) % 3, (tt + 2) * 32);
        stageB((tt + 2) % 3, (tt + 2) * 32);
      }
      const int rem = (tt + 2 < KT ? tt + 2 : KT - 1) - tt;
      if (rem >= 2)      asm volatile("s_waitcnt vmcnt(8)" ::: "memory");
      else if (rem == 1) asm volatile("s_waitcnt vmcnt(4)" ::: "memory");
      else               asm volatile("s_waitcnt vmcnt(0)" ::: "memory");
    }
    __builtin_amdgcn_s_barrier();        // B2: tile tt visible to all
    __builtin_amdgcn_sched_barrier(0);
    compute(tt % 3);
  }

#pragma unroll
  for (int m = 0; m < 4; ++m)
#pragma unroll
    for (int n = 0; n < 4; ++n) {
      const f32x4 v = acc[m][n];
      const int col = n0 + wc * 64 + n * 16 + lr;
      const int rbase = m0 + wr * 64 + m * 16 + lk * 4;
      float bv = 0.f;
      if (HAS_BIAS) bv = bias[col];
#pragma unroll
      for (int r = 0; r < 4; ++r) {
        const float val = v[r] + bv;
        if (OUT_MODE == 0) {
          ((float*)Cv)[(size_t)(rbase + r) * ldc + col] = val;
        } else if (OUT_MODE == 1) {
          ((unsigned short*)Cv)[(size_t)(rbase + r) * ldc + col] = f2bf(val);
        } else {
          unsigned char* Cb = (unsigned char*)Cv;
          const size_t rb = (size_t)(rbase + r) * 768;
          if (col < 256) {
            Cb[rb + col] = f2fp8(val);
          } else {
            *(unsigned short*)(Cb + rb + 256 + (size_t)(col - 256) * 2) = f2bf(val);
          }
        }
      }
    }
}

// All three projections in ONE dispatch, reading fp32 sources directly:
// blocks [0,2048): KV (support fp32, OUT_MODE=2: fp8 K | bf16 V, 768 B rows)
// blocks [2048,2176): Qf (query fp32) ; [2176,2304): Gf (geo fp32, K=64)
__global__ __launch_bounds__(256) void proj(
    const float* __restrict__ support, const float* __restrict__ query,
    const float* __restrict__ geo,
    const unsigned short* __restrict__ Btkv, const unsigned short* __restrict__ Btq,
    const unsigned short* __restrict__ Btg,
    unsigned char* __restrict__ KV, unsigned short* __restrict__ Qf,
    unsigned short* __restrict__ Gf) {
  __shared__ unsigned short As[3][128 * 32];
  __shared__ unsigned short Bs[3][128 * 32];
  const int b = blockIdx.x;
  if (b < 2048) {
    gemm_body<8, true, 2, false>(support, Btkv, KV, nullptr, 0, b, 4, 2048, As, Bs);
  } else if (b < 2176) {
    gemm_body<8, true, 1, false>(query, Btq, Qf, nullptr, 256, b - 2048, 2, 128, As, Bs);
  } else {
    gemm_body<2, true, 1, false>(geo, Btg, Gf, nullptr, 256, b - 2176, 2, 128, As, Bs);
  }
}

// Final: out = Opre(bf16) @ Wo^T + bo (fp32 out).
__global__ __launch_bounds__(256) void gemm_final(
    const unsigned short* __restrict__ A, const unsigned short* __restrict__ Bt,
    void* __restrict__ C, const float* __restrict__ bias) {
  __shared__ unsigned short As[3][128 * 32];
  __shared__ unsigned short Bs[3][128 * 32];
  gemm_body<8, false, 0, true>(A, Bt, C, bias, 256, blockIdx.x, 2, 128, As, Bs);
}

// One block (256 thr) per query; 8 edge streams; 32 lanes per edge.
// KV row (768 B) = K fp8 e4m3 (256 B) | V bf16 (512 B). Depth-2 prefetch.
// No online max (exact; scores bounded).
__global__ __launch_bounds__(256) void edge_attn(
    const int* __restrict__ s_idx, const int* __restrict__ q_start,
    const unsigned char* __restrict__ KVb, const unsigned short* __restrict__ Qf,
    const unsigned short* __restrict__ Gf, unsigned short* __restrict__ out_pre,
    const float* __restrict__ log_tau) {
  const int q = blockIdx.x;
  const int t = threadIdx.x;
  const int w = t >> 6;
  const int lane = t & 63;
  const int stream = w * 2 + (lane >> 5);
  const int sl = lane & 31;
  const int start = q_start[q], end = q_start[q + 1];

  const float tau = __expf(log_tau[0]);
  const float rs = 1.0f / (5.656854249492381f * tau);

  float qv[8];
  {
    uint4 qw = *(const uint4*)(Qf + (size_t)q * 256 + sl * 8);
    const unsigned int ws_[4] = {qw.x, qw.y, qw.z, qw.w};
#pragma unroll
    for (int j = 0; j < 4; ++j) {
      qv[2 * j]     = bf2f((unsigned short)(ws_[j] & 0xffffu)) * rs;
      qv[2 * j + 1] = bf2f((unsigned short)(ws_[j] >> 16)) * rs;
    }
  }

  float o[8];
#pragma unroll
  for (int j = 0; j < 8; ++j) o[j] = 0.f;
  float lsum_p = 0.f;

  __shared__ int sseg[1024];

  for (int cb = start; cb < end; cb += 1024) {
    const int nb = min(1024, end - cb);
    __syncthreads();
    for (int jj = t; jj < nb; jj += 256) sseg[jj] = s_idx[cb + jj];
    __syncthreads();

    int j = stream;
    uint2 kc = {}, kn = {};
    uint4 vc = {}, vn = {};
    if (j < nb) {
      const unsigned char* bp = KVb + (size_t)sseg[j] * 768;
      kc = *(const uint2*)(bp + sl * 8);
      vc = *(const uint4*)(bp + 256 + sl * 16);
    }
    if (j + 8 < nb) {
      const unsigned char* bp = KVb + (size_t)sseg[j + 8] * 768;
      kn = *(const uint2*)(bp + sl * 8);
      vn = *(const uint4*)(bp + 256 + sl * 16);
    }
    while (j < nb) {
      const int j2 = j + 16;
      uint2 k2 = {};
      uint4 v2 = {};
      if (j2 < nb) {
        const unsigned char* bp = KVb + (size_t)sseg[j2] * 768;
        k2 = *(const uint2*)(bp + sl * 8);
        v2 = *(const uint4*)(bp + 256 + sl * 16);
      }
      float kf[8];
      fp8x4_to_f32(kc.x, kf);
      fp8x4_to_f32(kc.y, kf + 4);
      float p = 0.f;
#pragma unroll
      for (int jj = 0; jj < 8; ++jj) p = fmaf(qv[jj], kf[jj], p);
      p += __shfl_xor(p, 1);
      p += __shfl_xor(p, 2);
      const float ew = __expf(p);
      lsum_p += ew;
      const unsigned int vw[4] = {vc.x, vc.y, vc.z, vc.w};
#pragma unroll
      for (int jj = 0; jj < 4; ++jj) {
        o[2 * jj]     = fmaf(ew, bf2f((unsigned short)(vw[jj] & 0xffffu)), o[2 * jj]);
        o[2 * jj + 1] = fmaf(ew, bf2f((unsigned short)(vw[jj] >> 16)), o[2 * jj + 1]);
      }
      j += 8;
      kc = kn; vc = vn;
      kn = k2; vn = v2;
    }
  }

  __shared__ float o_sh[8][256];
  __shared__ float l_sh[8][8];
  *(float4*)&o_sh[stream][sl * 8]     = (float4){o[0], o[1], o[2], o[3]};
  *(float4*)&o_sh[stream][sl * 8 + 4] = (float4){o[4], o[5], o[6], o[7]};
  if ((sl & 3) == 0) l_sh[stream][sl >> 2] = lsum_p;
  __syncthreads();

  float osum = 0.f, lsum = 0.f;
  const int h = t >> 5;
#pragma unroll
  for (int s = 0; s < 8; ++s) {
    osum += o_sh[s][t];
    lsum += l_sh[s][h];
  }
  const float inv = 1.0f / fmaxf(lsum, 1e-8f);
  float res = 0.f;
  if (end > start) res = osum * inv + (lsum * inv) * bf2f(Gf[(size_t)q * 256 + t]);
  out_pre[(size_t)q * 256 + t] = f2bf(res);
}

extern "C" void kernel_launch(void* const* d_in, const int* in_sizes, int n_in,
                              void* d_out, int out_size, void* d_ws, size_t ws_size,
                              hipStream_t stream) {
  const float* query   = (const float*)d_in[0];
  const float* support = (const float*)d_in[1];
  const float* geo     = (const float*)d_in[2];
  const int*   q_idx   = (const int*)d_in[3];
  const int*   s_idx   = (const int*)d_in[4];
  const float* Wq      = (const float*)d_in[6];
  const float* Wk      = (const float*)d_in[7];
  const float* Wv      = (const float*)d_in[8];
  const float* Wg      = (const float*)d_in[9];
  const float* Wo      = (const float*)d_in[10];
  const float* bo      = (const float*)d_in[11];
  const float* log_tau = (const float*)d_in[12];

  const int D = 256;
  const int Q = in_sizes[0] / D;   // 8192
  const int N = in_sizes[1] / D;   // 65536
  const int E = in_sizes[3];       // 262144

  unsigned char* wsb = (unsigned char*)d_ws;
  unsigned char*  KV   = wsb;                                       // [N][768]
  unsigned short* Qf   = (unsigned short*)(wsb + (size_t)N * 768);  // [Q][256]
  unsigned short* Gf   = Qf   + (size_t)Q * 256;   // [Q][256]
  unsigned short* Opre = Gf   + (size_t)Q * 256;   // [Q][256]
  unsigned short* Btkv = Opre + (size_t)Q * 256;   // [512][256] = [Wk^T; Wv^T]
  unsigned short* Btq  = Btkv + 512 * 256;         // [256][256]
  unsigned short* Btg  = Btq  + 256 * 256;         // [256][64]
  unsigned short* Bto  = Btg  + 256 * 64;          // [256][256]
  int* q_start = (int*)(Bto + 256 * 256);          // [Q+1]

  dim3 blk(256);

  prep<<<dim3(305), blk, 0, stream>>>(Wk, Wv, Wq, Wo, Wg,
                                      Btkv, Btq, Bto, Btg, q_idx, q_start, Q, E);

  // KV + Qf + Gf projections (fused fp32->bf16 A cast) in one dispatch
  proj<<<dim3(2304), blk, 0, stream>>>(support, query, geo, Btkv, Btq, Btg,
                                       KV, Qf, Gf);

  edge_attn<<<dim3(Q), blk, 0, stream>>>(s_idx, q_start, KV,
                                         Qf, Gf, Opre, log_tau);

  gemm_final<<<dim3(128), blk, 0, stream>>>(Opre, Bto, d_out, bo);
}